// Round 8
// baseline (474.275 us; speedup 1.0000x reference)
//
#include <hip/hip_runtime.h>

// B=16, C=1, H=512, W=640
#define BB 16
#define HH 512
#define WW 640
constexpr int HW = HH * WW;

#define WT 64
#define HT 16
#define RP 4                 // center rows per thread
#define PAD 4
#define LW (WT + 2*PAD)      // 72 (left+right halo)
#define LH (HT + PAD)        // 20 (bottom halo only; pair symmetry needs no top)
#define LHW (LH * LW)        // 1440
#define NIT ((LHW + 255) / 256)  // 6
#define GX (WW / WT)         // 10
#define GY (HH / HT)         // 32
#define NBLK (GX * GY * BB)  // 5120

constexpr float HALO = 1.0e6f;   // OOB fill: both signs +1 -> c=0

__device__ __forceinline__ float fast_rcp(float x) {
    return __builtin_amdgcn_rcpf(x);
}

// ---- channel-mean of pattern: 1.3 MB, stays L2/LIC resident
__global__ __launch_bounds__(256)
void pm_kernel(const float* __restrict__ pattern, float* __restrict__ pm)
{
    int i = blockIdx.x * 256 + threadIdx.x;
    if (i < HW)
        pm[i] = (pattern[i] + pattern[HW + i] + pattern[2 * HW + i]) * (1.0f / 3.0f);
}

// ---- interior census: wave-scalar ballot/popcount, all pair weights 2/81
__device__ __forceinline__ unsigned census_interior(const float2* sm, int tx, int rg)
{
    float ehi[RP], elo[RP], thi[RP], tlo[RP];
    #pragma unroll
    for (int p = 0; p < RP; ++p) {
        float2 c = sm[(rg * RP + p) * LW + tx + PAD];
        ehi[p] = c.x + 0.5f;  elo[p] = c.x - 0.5f;
        thi[p] = c.y + 0.5f;  tlo[p] = c.y - 0.5f;
    }
    unsigned acc = 0;
    #pragma unroll
    for (int wr = 0; wr < RP + PAD; ++wr) {
        const float2* row = sm + (rg * RP + wr) * LW + tx;
        float2 v[9];
        #pragma unroll
        for (int j = 0; j < 9; ++j) v[j] = row[j];
        #pragma unroll
        for (int p = 0; p < RP; ++p) {
            if (p == wr) {                       // dh==0, forward cols only
                #pragma unroll
                for (int j = 5; j <= 8; ++j) {
                    unsigned long long mh = __ballot(v[j].x > ehi[p]) ^ __ballot(v[j].y > thi[p]);
                    unsigned long long ml = __ballot(v[j].x < elo[p]) ^ __ballot(v[j].y < tlo[p]);
                    acc += (unsigned)__popcll(mh) + (unsigned)__popcll(ml);
                }
            } else if (p >= wr - PAD && p < wr) {  // dh = wr-p in 1..4
                #pragma unroll
                for (int j = 0; j <= 8; ++j) {
                    unsigned long long mh = __ballot(v[j].x > ehi[p]) ^ __ballot(v[j].y > thi[p]);
                    unsigned long long ml = __ballot(v[j].x < elo[p]) ^ __ballot(v[j].y < tlo[p]);
                    acc += (unsigned)__popcll(mh) + (unsigned)__popcll(ml);
                }
            }
        }
    }
    return acc;   // wave-uniform: total taps over this wave's 64 cols x 4 center rows
}

// ---- edge census: per-lane, pair weight = 1/cnt_p + 1/cnt_q (exact)
__device__ __forceinline__ float census_edge(const float2* sm, int tx, int rg,
                                             int bx, int by)
{
    float invcw[9];
    const int w0 = bx * WT + tx;
    #pragma unroll
    for (int j = 0; j < 9; ++j) {
        int c  = w0 + j - PAD;                  // may be OOB (cw>=1, tap c=0 there)
        int cw = min(PAD, WW - 1 - c) + min(PAD, c) + 1;
        invcw[j] = fast_rcp((float)cw);
    }

    float ehi[RP], elo[RP], thi[RP], tlo[RP], wp[RP], facc[RP];
    int iacc[RP];
    #pragma unroll
    for (int p = 0; p < RP; ++p) {
        float2 c = sm[(rg * RP + p) * LW + tx + PAD];
        ehi[p] = c.x + 0.5f;  elo[p] = c.x - 0.5f;
        thi[p] = c.y + 0.5f;  tlo[p] = c.y - 0.5f;
        int r  = by * HT + rg * RP + p;
        int ch = min(PAD, HH - 1 - r) + min(PAD, r) + 1;
        wp[p]  = fast_rcp((float)ch) * invcw[PAD];   // center's own 1/count
        facc[p] = 0.0f;
        iacc[p] = 0;
    }

    #pragma unroll
    for (int wr = 0; wr < RP + PAD; ++wr) {
        int r  = by * HT + rg * RP + wr;        // may exceed HH-1 (tap c=0 there)
        int ch = min(PAD, HH - 1 - r) + min(PAD, r) + 1;
        float rowinv = fast_rcp((float)ch);
        float wq[9];
        #pragma unroll
        for (int j = 0; j < 9; ++j) wq[j] = rowinv * invcw[j];

        const float2* row = sm + (rg * RP + wr) * LW + tx;
        float2 v[9];
        #pragma unroll
        for (int j = 0; j < 9; ++j) v[j] = row[j];

        #pragma unroll
        for (int p = 0; p < RP; ++p) {
            const bool d0 = (p == wr);
            if (p <= wr && p >= wr - PAD) {
                #pragma unroll
                for (int j = 0; j <= 8; ++j) {
                    if (d0 && j <= 4) continue;   // dh==0: forward cols only
                    int bh = (int)((v[j].x > ehi[p]) != (v[j].y > thi[p]));
                    int bl = (int)((v[j].x < elo[p]) != (v[j].y < tlo[p]));
                    int c  = bh + bl;
                    facc[p] = fmaf((float)c, wq[j], facc[p]);  // partner weights
                    iacc[p] += c;                              // for self weight
                }
            }
        }
    }
    float sum = 0.0f;
    #pragma unroll
    for (int p = 0; p < RP; ++p)
        sum += facc[p] + wp[p] * (float)iacc[p];
    return sum;   // per-lane, caller shuffle-reduces
}

__global__ __launch_bounds__(256, 6)
void fused_kernel(const float* __restrict__ disp0,
                  const float* __restrict__ im,
                  const float* __restrict__ pm,
                  float* __restrict__ out,       // [val, proj...]
                  float* __restrict__ partial)   // NBLK floats
{
    __shared__ float2 sm[LHW];
    __shared__ float wsum[4];

    const int bx = blockIdx.x, by = blockIdx.y, b = blockIdx.z;
    const int tx = threadIdx.x;      // 0..63
    const int rg = threadIdx.y;      // 0..3
    const int tid = rg * 64 + tx;

    const float* db = disp0 + (size_t)b * HW;
    const float* ib = im    + (size_t)b * HW;
    float* proj = out + 1 + (size_t)b * HW;

    const int gh0 = by * HT;           // LDS row 0 == tile top (no top halo)
    const int gw0 = bx * WT - PAD;     // LDS col 0

    // ---- phase 1: batch the coalesced disp/im loads (independent, ILP)
    float dv[NIT], tv[NIT];
    #pragma unroll
    for (int it = 0; it < NIT; ++it) {
        int i = tid + it * 256;
        int lh = i / LW, lw = i - lh * LW;
        int gh = gh0 + lh, gw = gw0 + lw;
        bool ok = (i < LHW) & (gh < HH) & (gw >= 0) & (gw < WW);
        int g = gh * WW + gw;
        dv[it] = ok ? db[g] : 0.0f;
        tv[it] = ok ? ib[g] : HALO;
    }
    // ---- phase 2: L2-resident pm gathers + lerp, write LDS + proj
    #pragma unroll
    for (int it = 0; it < NIT; ++it) {
        int i = tid + it * 256;
        if (i < LHW) {
            int lh = i / LW, lw = i - lh * LW;
            int gh = gh0 + lh, gw = gw0 + lw;
            float ev = HALO;
            if ((gh < HH) & (gw >= 0) & (gw < WW)) {
                int g = gh * WW + gw;
                float x = fminf(fmaxf((float)gw - dv[it], 0.0f), (float)(WW - 1));
                int   x0 = (int)x;
                int   x1 = min(x0 + 1, WW - 1);
                float w  = x - (float)x0;
                const float* pr = pm + gh * WW;
                float p0 = pr[x0], p1 = pr[x1];
                ev = p0 * (1.0f - w) + p1 * w;
                if ((lh < HT) & (lw >= PAD) & (lw < PAD + WT))
                    proj[g] = ev;
            }
            sm[i] = make_float2(ev, tv[it]);
        }
    }
    __syncthreads();

    // ---- census
    if ((bx >= 1) & (bx <= GX - 2) & (by >= 1) & (by <= GY - 2)) {
        unsigned acc = census_interior(sm, tx, rg);
        if (tx == 0) wsum[rg] = (float)acc * (2.0f / 81.0f);
    } else {
        float tsum = census_edge(sm, tx, rg, bx, by);
        #pragma unroll
        for (int off = 32; off > 0; off >>= 1)
            tsum += __shfl_down(tsum, off, 64);
        if (tx == 0) wsum[rg] = tsum;
    }
    __syncthreads();
    if (tid == 0)
        partial[(b * GY + by) * GX + bx] = wsum[0] + wsum[1] + wsum[2] + wsum[3];
}

__global__ __launch_bounds__(256)
void reduce_kernel(const float* __restrict__ partial, float* __restrict__ out)
{
    __shared__ float wsum[4];
    int t = threadIdx.x;
    float s = 0.0f;
    #pragma unroll
    for (int i = 0; i < NBLK / 256; ++i) s += partial[t + i * 256];
    #pragma unroll
    for (int off = 32; off > 0; off >>= 1)
        s += __shfl_down(s, off, 64);
    if ((t & 63) == 0) wsum[t >> 6] = s;
    __syncthreads();
    if (t == 0)
        out[0] = (wsum[0] + wsum[1] + wsum[2] + wsum[3]) * (1.0f / ((float)BB * (float)HW));
}

extern "C" void kernel_launch(void* const* d_in, const int* in_sizes, int n_in,
                              void* d_out, int out_size, void* d_ws, size_t ws_size,
                              hipStream_t stream) {
    const float* disp0   = (const float*)d_in[0];
    const float* im      = (const float*)d_in[1];
    const float* pattern = (const float*)d_in[2];
    float* out = (float*)d_out;
    float* pm      = (float*)d_ws;        // HW floats = 1.31 MB (L2-resident)
    float* partial = pm + HW;             // NBLK floats

    pm_kernel<<<(HW + 255) / 256, 256, 0, stream>>>(pattern, pm);

    dim3 grid(GX, GY, BB);                // 10, 32, 16
    dim3 block(64, 4);
    fused_kernel<<<grid, block, 0, stream>>>(disp0, im, pm, out, partial);
    reduce_kernel<<<1, 256, 0, stream>>>(partial, out);
}

// Round 9
// 462.693 us; speedup vs baseline: 1.0250x; 1.0250x over previous
//
#include <hip/hip_runtime.h>

// B=16, C=1, H=512, W=640
#define BB 16
#define HH 512
#define WW 640
constexpr int HW = HH * WW;

#define WT 64
#define HT 16
#define RP 4                 // center rows per thread
#define PAD 4
#define LW (WT + 2*PAD)      // 72 (left+right halo)
#define LH (HT + PAD)        // 20 (bottom halo only; pair symmetry needs no top)
#define LHW (LH * LW)        // 1440
#define NIT ((LHW + 255) / 256)  // 6
#define GX (WW / WT)         // 10
#define GY (HH / HT)         // 32
#define NBLK (GX * GY * BB)  // 5120

constexpr float HALO = 1.0e6f;   // OOB fill: both signs +1 -> c=0

__device__ __forceinline__ float fast_rcp(float x) {
    return __builtin_amdgcn_rcpf(x);
}

// ---- channel-mean of pattern: 1.3 MB, stays L2/LIC resident
__global__ __launch_bounds__(256)
void pm_kernel(const float* __restrict__ pattern, float* __restrict__ pm)
{
    int i = blockIdx.x * 256 + threadIdx.x;
    if (i < HW)
        pm[i] = (pattern[i] + pattern[HW + i] + pattern[2 * HW + i]) * (1.0f / 3.0f);
}

// ---- interior census: wave-scalar ballot/popcount, all pair weights 2/81
__device__ __forceinline__ unsigned census_interior(const float2* sm, int tx, int rg)
{
    float ehi[RP], elo[RP], thi[RP], tlo[RP];
    #pragma unroll
    for (int p = 0; p < RP; ++p) {
        float2 c = sm[(rg * RP + p) * LW + tx + PAD];
        ehi[p] = c.x + 0.5f;  elo[p] = c.x - 0.5f;
        thi[p] = c.y + 0.5f;  tlo[p] = c.y - 0.5f;
    }
    unsigned acc = 0;
    #pragma unroll
    for (int wr = 0; wr < RP + PAD; ++wr) {
        const float2* row = sm + (rg * RP + wr) * LW + tx;
        float2 v[9];
        #pragma unroll
        for (int j = 0; j < 9; ++j) v[j] = row[j];
        #pragma unroll
        for (int p = 0; p < RP; ++p) {
            if (p == wr) {                       // dh==0, forward cols only
                #pragma unroll
                for (int j = 5; j <= 8; ++j) {
                    unsigned long long mh = __ballot(v[j].x > ehi[p]) ^ __ballot(v[j].y > thi[p]);
                    unsigned long long ml = __ballot(v[j].x < elo[p]) ^ __ballot(v[j].y < tlo[p]);
                    acc += (unsigned)__popcll(mh) + (unsigned)__popcll(ml);
                }
            } else if (p >= wr - PAD && p < wr) {  // dh = wr-p in 1..4
                #pragma unroll
                for (int j = 0; j <= 8; ++j) {
                    unsigned long long mh = __ballot(v[j].x > ehi[p]) ^ __ballot(v[j].y > thi[p]);
                    unsigned long long ml = __ballot(v[j].x < elo[p]) ^ __ballot(v[j].y < tlo[p]);
                    acc += (unsigned)__popcll(mh) + (unsigned)__popcll(ml);
                }
            }
        }
    }
    return acc;   // wave-uniform: total taps over this wave's 64 cols x 4 center rows
}

// ---- edge census: per-lane, pair weight = 1/cnt_p + 1/cnt_q (exact)
__device__ __forceinline__ float census_edge(const float2* sm, int tx, int rg,
                                             int bx, int by)
{
    float invcw[9];
    const int w0 = bx * WT + tx;
    #pragma unroll
    for (int j = 0; j < 9; ++j) {
        int c  = w0 + j - PAD;                  // may be OOB (cw>=1, tap c=0 there)
        int cw = min(PAD, WW - 1 - c) + min(PAD, c) + 1;
        invcw[j] = fast_rcp((float)cw);
    }

    float ehi[RP], elo[RP], thi[RP], tlo[RP], wp[RP], facc[RP];
    int iacc[RP];
    #pragma unroll
    for (int p = 0; p < RP; ++p) {
        float2 c = sm[(rg * RP + p) * LW + tx + PAD];
        ehi[p] = c.x + 0.5f;  elo[p] = c.x - 0.5f;
        thi[p] = c.y + 0.5f;  tlo[p] = c.y - 0.5f;
        int r  = by * HT + rg * RP + p;
        int ch = min(PAD, HH - 1 - r) + min(PAD, r) + 1;
        wp[p]  = fast_rcp((float)ch) * invcw[PAD];   // center's own 1/count
        facc[p] = 0.0f;
        iacc[p] = 0;
    }

    #pragma unroll
    for (int wr = 0; wr < RP + PAD; ++wr) {
        int r  = by * HT + rg * RP + wr;        // may exceed HH-1 (tap c=0 there)
        int ch = min(PAD, HH - 1 - r) + min(PAD, r) + 1;
        float rowinv = fast_rcp((float)ch);
        float wq[9];
        #pragma unroll
        for (int j = 0; j < 9; ++j) wq[j] = rowinv * invcw[j];

        const float2* row = sm + (rg * RP + wr) * LW + tx;
        float2 v[9];
        #pragma unroll
        for (int j = 0; j < 9; ++j) v[j] = row[j];

        #pragma unroll
        for (int p = 0; p < RP; ++p) {
            const bool d0 = (p == wr);
            if (p <= wr && p >= wr - PAD) {
                #pragma unroll
                for (int j = 0; j <= 8; ++j) {
                    if (d0 && j <= 4) continue;   // dh==0: forward cols only
                    int bh = (int)((v[j].x > ehi[p]) != (v[j].y > thi[p]));
                    int bl = (int)((v[j].x < elo[p]) != (v[j].y < tlo[p]));
                    int c  = bh + bl;
                    facc[p] = fmaf((float)c, wq[j], facc[p]);  // partner weights
                    iacc[p] += c;                              // for self weight
                }
            }
        }
    }
    float sum = 0.0f;
    #pragma unroll
    for (int p = 0; p < RP; ++p)
        sum += facc[p] + wp[p] * (float)iacc[p];
    return sum;   // per-lane, caller shuffle-reduces
}

__global__ __launch_bounds__(256)   // NO min-waves arg: round 8's (256,6) capped
void fused_kernel(const float* __restrict__ disp0,   // VGPR at 40 -> 640MB of spills
                  const float* __restrict__ im,
                  const float* __restrict__ pm,
                  float* __restrict__ out,       // [val, proj...]
                  float* __restrict__ partial)   // NBLK floats
{
    __shared__ float2 sm[LHW];
    __shared__ float wsum[4];

    const int bx = blockIdx.x, by = blockIdx.y, b = blockIdx.z;
    const int tx = threadIdx.x;      // 0..63
    const int rg = threadIdx.y;      // 0..3
    const int tid = rg * 64 + tx;

    const float* db = disp0 + (size_t)b * HW;
    const float* ib = im    + (size_t)b * HW;
    float* proj = out + 1 + (size_t)b * HW;

    const int gh0 = by * HT;           // LDS row 0 == tile top (no top halo)
    const int gw0 = bx * WT - PAD;     // LDS col 0

    // ---- phase 1: batch the coalesced disp/im loads (independent, ILP)
    float dv[NIT], tv[NIT];
    #pragma unroll
    for (int it = 0; it < NIT; ++it) {
        int i = tid + it * 256;
        int lh = i / LW, lw = i - lh * LW;
        int gh = gh0 + lh, gw = gw0 + lw;
        bool ok = (i < LHW) & (gh < HH) & (gw >= 0) & (gw < WW);
        int g = gh * WW + gw;
        dv[it] = ok ? db[g] : 0.0f;
        tv[it] = ok ? ib[g] : HALO;
    }
    // ---- phase 2: L2-resident pm gathers + lerp, write LDS + proj
    #pragma unroll
    for (int it = 0; it < NIT; ++it) {
        int i = tid + it * 256;
        if (i < LHW) {
            int lh = i / LW, lw = i - lh * LW;
            int gh = gh0 + lh, gw = gw0 + lw;
            float ev = HALO;
            if ((gh < HH) & (gw >= 0) & (gw < WW)) {
                int g = gh * WW + gw;
                float x = fminf(fmaxf((float)gw - dv[it], 0.0f), (float)(WW - 1));
                int   x0 = (int)x;
                int   x1 = min(x0 + 1, WW - 1);
                float w  = x - (float)x0;
                const float* pr = pm + gh * WW;
                float p0 = pr[x0], p1 = pr[x1];
                ev = p0 * (1.0f - w) + p1 * w;
                if ((lh < HT) & (lw >= PAD) & (lw < PAD + WT))
                    proj[g] = ev;
            }
            sm[i] = make_float2(ev, tv[it]);
        }
    }
    __syncthreads();

    // ---- census
    if ((bx >= 1) & (bx <= GX - 2) & (by >= 1) & (by <= GY - 2)) {
        unsigned acc = census_interior(sm, tx, rg);
        if (tx == 0) wsum[rg] = (float)acc * (2.0f / 81.0f);
    } else {
        float tsum = census_edge(sm, tx, rg, bx, by);
        #pragma unroll
        for (int off = 32; off > 0; off >>= 1)
            tsum += __shfl_down(tsum, off, 64);
        if (tx == 0) wsum[rg] = tsum;
    }
    __syncthreads();
    if (tid == 0)
        partial[(b * GY + by) * GX + bx] = wsum[0] + wsum[1] + wsum[2] + wsum[3];
}

__global__ __launch_bounds__(256)
void reduce_kernel(const float* __restrict__ partial, float* __restrict__ out)
{
    __shared__ float wsum[4];
    int t = threadIdx.x;
    float s = 0.0f;
    #pragma unroll
    for (int i = 0; i < NBLK / 256; ++i) s += partial[t + i * 256];
    #pragma unroll
    for (int off = 32; off > 0; off >>= 1)
        s += __shfl_down(s, off, 64);
    if ((t & 63) == 0) wsum[t >> 6] = s;
    __syncthreads();
    if (t == 0)
        out[0] = (wsum[0] + wsum[1] + wsum[2] + wsum[3]) * (1.0f / ((float)BB * (float)HW));
}

extern "C" void kernel_launch(void* const* d_in, const int* in_sizes, int n_in,
                              void* d_out, int out_size, void* d_ws, size_t ws_size,
                              hipStream_t stream) {
    const float* disp0   = (const float*)d_in[0];
    const float* im      = (const float*)d_in[1];
    const float* pattern = (const float*)d_in[2];
    float* out = (float*)d_out;
    float* pm      = (float*)d_ws;        // HW floats = 1.31 MB (L2-resident)
    float* partial = pm + HW;             // NBLK floats

    pm_kernel<<<(HW + 255) / 256, 256, 0, stream>>>(pattern, pm);

    dim3 grid(GX, GY, BB);                // 10, 32, 16
    dim3 block(64, 4);
    fused_kernel<<<grid, block, 0, stream>>>(disp0, im, pm, out, partial);
    reduce_kernel<<<1, 256, 0, stream>>>(partial, out);
}

// Round 10
// 173.120 us; speedup vs baseline: 2.7396x; 2.6727x over previous
//
#include <hip/hip_runtime.h>

// B=16, C=1, H=512, W=640
#define BB 16
#define HH 512
#define WW 640
constexpr int HW = HH * WW;

#define WT 64
#define HT 16
#define RP 4                 // center rows per thread
#define PAD 4
#define LW (WT + 2*PAD)      // 72
#define LH (HT + PAD)        // 20 (bottom halo only; pair symmetry needs no top)
#define LHW (LH * LW)        // 1440
#define NIT ((LHW + 255) / 256)  // 6
#define GX (WW / WT)         // 10
#define GY (HH / HT)         // 32
#define NBLK (GX * GY * BB)  // 5120

constexpr float HALO = 1.0e6f;   // OOB fill: both signs +1 -> c=0

__device__ __forceinline__ float fast_rcp(float x) {
    return __builtin_amdgcn_rcpf(x);
}

// ---- channel-mean of pattern: 1.3 MB, stays L2/LIC resident
__global__ __launch_bounds__(256)
void pm_kernel(const float* __restrict__ pattern, float* __restrict__ pm)
{
    int i = blockIdx.x * 256 + threadIdx.x;
    if (i < HW)
        pm[i] = (pattern[i] + pattern[HW + i] + pattern[2 * HW + i]) * (1.0f / 3.0f);
}

// ================= interior kernel: lean, no guards, per-lane XOR census ======
__global__ __launch_bounds__(256)
void interior_kernel(const float* __restrict__ disp0,
                     const float* __restrict__ im,
                     const float* __restrict__ pm,
                     float* __restrict__ out,       // [val, proj...]
                     float* __restrict__ partial)
{
    __shared__ float2 sm[LHW];
    __shared__ int wsum[4];

    const int bx = blockIdx.x + 1;   // 1..GX-2
    const int by = blockIdx.y + 1;   // 1..GY-2
    const int b  = blockIdx.z;
    const int tx = threadIdx.x, rg = threadIdx.y;
    const int tid = rg * 64 + tx;

    const float* db = disp0 + (size_t)b * HW;
    const float* ib = im    + (size_t)b * HW;
    float* proj = out + 1 + (size_t)b * HW;

    const int gh0 = by * HT;          // >=16; +19 <= 499  -> all rows in-bounds
    const int gw0 = bx * WT - PAD;    // >=60; +71 <= 579  -> all cols in-bounds

    // ---- phase 1: batched coalesced loads (independent -> ILP), no guards
    float dv[NIT], tv[NIT];
    #pragma unroll
    for (int it = 0; it < NIT; ++it) {
        int i = tid + it * 256;
        if (i < LHW) {
            int lh = i / LW, lw = i - lh * LW;
            int g = (gh0 + lh) * WW + (gw0 + lw);
            dv[it] = db[g];
            tv[it] = ib[g];
        }
    }
    // ---- phase 2: L2-resident pm gathers + lerp, write LDS + proj
    #pragma unroll
    for (int it = 0; it < NIT; ++it) {
        int i = tid + it * 256;
        if (i < LHW) {
            int lh = i / LW, lw = i - lh * LW;
            int gh = gh0 + lh, gw = gw0 + lw;
            int g = gh * WW + gw;
            float x = fminf(fmaxf((float)gw - dv[it], 0.0f), (float)(WW - 1));
            int   x0 = (int)x;
            int   x1 = min(x0 + 1, WW - 1);
            float w  = x - (float)x0;
            const float* pr = pm + gh * WW;
            float ev = pr[x0] * (1.0f - w) + pr[x1] * w;
            if ((lh < HT) & (lw >= PAD) & (lw < PAD + WT))
                proj[g] = ev;
            sm[i] = make_float2(ev, tv[it]);
        }
    }
    __syncthreads();

    // ---- census: per-lane XOR bits, 4 independent int chains
    float ehi[RP], elo[RP], thi[RP], tlo[RP];
    #pragma unroll
    for (int p = 0; p < RP; ++p) {
        float2 c = sm[(rg * RP + p) * LW + tx + PAD];
        ehi[p] = c.x + 0.5f;  elo[p] = c.x - 0.5f;
        thi[p] = c.y + 0.5f;  tlo[p] = c.y - 0.5f;
    }
    int acc[RP] = {0, 0, 0, 0};
    #pragma unroll
    for (int wr = 0; wr < RP + PAD; ++wr) {
        const float2* row = sm + (rg * RP + wr) * LW + tx;
        float2 v[9];
        #pragma unroll
        for (int j = 0; j < 9; ++j) v[j] = row[j];
        #pragma unroll
        for (int p = 0; p < RP; ++p) {
            int dh = wr - p;
            if (dh == 0) {                       // forward cols only
                #pragma unroll
                for (int j = 5; j <= 8; ++j) {
                    acc[p] += (int)((v[j].x > ehi[p]) != (v[j].y > thi[p]));
                    acc[p] += (int)((v[j].x < elo[p]) != (v[j].y < tlo[p]));
                }
            } else if (dh >= 1 && dh <= PAD) {
                #pragma unroll
                for (int j = 0; j <= 8; ++j) {
                    acc[p] += (int)((v[j].x > ehi[p]) != (v[j].y > thi[p]));
                    acc[p] += (int)((v[j].x < elo[p]) != (v[j].y < tlo[p]));
                }
            }
        }
    }
    int a = (acc[0] + acc[1]) + (acc[2] + acc[3]);
    #pragma unroll
    for (int off = 32; off > 0; off >>= 1)
        a += __shfl_down(a, off, 64);
    if (tx == 0) wsum[rg] = a;
    __syncthreads();
    if (tid == 0)
        partial[(b * GY + by) * GX + bx] =
            (float)(wsum[0] + wsum[1] + wsum[2] + wsum[3]) * (2.0f / 81.0f);
}

// ================= edge kernel: guarded staging, exact per-pair weights ======
__global__ __launch_bounds__(256)
void edge_kernel(const float* __restrict__ disp0,
                 const float* __restrict__ im,
                 const float* __restrict__ pm,
                 float* __restrict__ out,
                 float* __restrict__ partial)
{
    const int bx = blockIdx.x, by = blockIdx.y, b = blockIdx.z;
    if ((bx >= 1) & (bx <= GX - 2) & (by >= 1) & (by <= GY - 2)) return;

    __shared__ float2 sm[LHW];
    __shared__ float wsumf[4];

    const int tx = threadIdx.x, rg = threadIdx.y;
    const int tid = rg * 64 + tx;

    const float* db = disp0 + (size_t)b * HW;
    const float* ib = im    + (size_t)b * HW;
    float* proj = out + 1 + (size_t)b * HW;

    const int gh0 = by * HT;
    const int gw0 = bx * WT - PAD;

    #pragma unroll
    for (int it = 0; it < NIT; ++it) {
        int i = tid + it * 256;
        if (i < LHW) {
            int lh = i / LW, lw = i - lh * LW;
            int gh = gh0 + lh, gw = gw0 + lw;
            float ev = HALO, tv = HALO;
            if ((gh < HH) & (gw >= 0) & (gw < WW)) {
                int g = gh * WW + gw;
                float d = db[g];
                float x = fminf(fmaxf((float)gw - d, 0.0f), (float)(WW - 1));
                int   x0 = (int)x;
                int   x1 = min(x0 + 1, WW - 1);
                float w  = x - (float)x0;
                const float* pr = pm + gh * WW;
                ev = pr[x0] * (1.0f - w) + pr[x1] * w;
                tv = ib[g];
                if ((lh < HT) & (lw >= PAD) & (lw < PAD + WT))
                    proj[g] = ev;
            }
            sm[i] = make_float2(ev, tv);
        }
    }
    __syncthreads();

    float invcw[9];
    const int w0 = bx * WT + tx;
    #pragma unroll
    for (int j = 0; j < 9; ++j) {
        int c  = w0 + j - PAD;                  // may be OOB (cw>=1; tap c=0 there)
        int cw = min(PAD, WW - 1 - c) + min(PAD, c) + 1;
        invcw[j] = fast_rcp((float)cw);
    }

    float ehi[RP], elo[RP], thi[RP], tlo[RP], wp[RP], facc[RP];
    int iacc[RP];
    #pragma unroll
    for (int p = 0; p < RP; ++p) {
        float2 c = sm[(rg * RP + p) * LW + tx + PAD];
        ehi[p] = c.x + 0.5f;  elo[p] = c.x - 0.5f;
        thi[p] = c.y + 0.5f;  tlo[p] = c.y - 0.5f;
        int r  = by * HT + rg * RP + p;
        int ch = min(PAD, HH - 1 - r) + min(PAD, r) + 1;
        wp[p]  = fast_rcp((float)ch) * invcw[PAD];   // center's own 1/count
        facc[p] = 0.0f;
        iacc[p] = 0;
    }

    #pragma unroll
    for (int wr = 0; wr < RP + PAD; ++wr) {
        int r  = by * HT + rg * RP + wr;        // may exceed HH-1 (tap c=0 there)
        int ch = min(PAD, HH - 1 - r) + min(PAD, r) + 1;
        float rowinv = fast_rcp((float)ch);

        const float2* row = sm + (rg * RP + wr) * LW + tx;
        float2 v[9];
        #pragma unroll
        for (int j = 0; j < 9; ++j) v[j] = row[j];

        #pragma unroll
        for (int p = 0; p < RP; ++p) {
            const bool d0 = (p == wr);
            if (p <= wr && p >= wr - PAD) {
                #pragma unroll
                for (int j = 0; j <= 8; ++j) {
                    if (d0 && j <= 4) continue;   // dh==0: forward cols only
                    int bh = (int)((v[j].x > ehi[p]) != (v[j].y > thi[p]));
                    int bl = (int)((v[j].x < elo[p]) != (v[j].y < tlo[p]));
                    int c  = bh + bl;
                    facc[p] = fmaf((float)c, rowinv * invcw[j], facc[p]);
                    iacc[p] += c;
                }
            }
        }
    }
    float tsum = 0.0f;
    #pragma unroll
    for (int p = 0; p < RP; ++p)
        tsum += facc[p] + wp[p] * (float)iacc[p];

    #pragma unroll
    for (int off = 32; off > 0; off >>= 1)
        tsum += __shfl_down(tsum, off, 64);
    if (tx == 0) wsumf[rg] = tsum;
    __syncthreads();
    if (tid == 0)
        partial[(b * GY + by) * GX + bx] = wsumf[0] + wsumf[1] + wsumf[2] + wsumf[3];
}

__global__ __launch_bounds__(256)
void reduce_kernel(const float* __restrict__ partial, float* __restrict__ out)
{
    __shared__ float wsum[4];
    int t = threadIdx.x;
    float s = 0.0f;
    #pragma unroll
    for (int i = 0; i < NBLK / 256; ++i) s += partial[t + i * 256];
    #pragma unroll
    for (int off = 32; off > 0; off >>= 1)
        s += __shfl_down(s, off, 64);
    if ((t & 63) == 0) wsum[t >> 6] = s;
    __syncthreads();
    if (t == 0)
        out[0] = (wsum[0] + wsum[1] + wsum[2] + wsum[3]) * (1.0f / ((float)BB * (float)HW));
}

extern "C" void kernel_launch(void* const* d_in, const int* in_sizes, int n_in,
                              void* d_out, int out_size, void* d_ws, size_t ws_size,
                              hipStream_t stream) {
    const float* disp0   = (const float*)d_in[0];
    const float* im      = (const float*)d_in[1];
    const float* pattern = (const float*)d_in[2];
    float* out = (float*)d_out;
    float* pm      = (float*)d_ws;        // HW floats = 1.31 MB (L2-resident)
    float* partial = pm + HW;             // NBLK floats

    pm_kernel<<<(HW + 255) / 256, 256, 0, stream>>>(pattern, pm);

    dim3 block(64, 4);
    dim3 gridI(GX - 2, GY - 2, BB);       // 8, 30, 16 = 3840 interior blocks
    interior_kernel<<<gridI, block, 0, stream>>>(disp0, im, pm, out, partial);

    dim3 gridE(GX, GY, BB);               // edge blocks do work; interior exit
    edge_kernel<<<gridE, block, 0, stream>>>(disp0, im, pm, out, partial);

    reduce_kernel<<<1, 256, 0, stream>>>(partial, out);
}